// Round 4
// baseline (155.951 us; speedup 1.0000x reference)
//
#include <hip/hip_runtime.h>

// StableZeroDiv: out = x * (y != 0 ? 1/y : 0), elementwise fp32.
// B*N = 67,108,864 fp32 elements per tensor. Pure streaming, HBM-bound:
// 768 MB total traffic -> ~122 us floor at 6.3 TB/s achievable.

__global__ void __launch_bounds__(256)
StableZeroDiv_16561393894029_kernel(const float4* __restrict__ x4,
                                    const float4* __restrict__ y4,
                                    float4* __restrict__ o4,
                                    int n4) {
    const int stride = gridDim.x * blockDim.x;
    for (int i = blockIdx.x * blockDim.x + threadIdx.x; i < n4; i += stride) {
        float4 xv = x4[i];
        float4 yv = y4[i];
        float4 ov;
        // Branchless safe division: IEEE divide when y != 0, else exact 0.
        ov.x = (yv.x != 0.0f) ? xv.x * (1.0f / yv.x) : 0.0f;
        ov.y = (yv.y != 0.0f) ? xv.y * (1.0f / yv.y) : 0.0f;
        ov.z = (yv.z != 0.0f) ? xv.z * (1.0f / yv.z) : 0.0f;
        ov.w = (yv.w != 0.0f) ? xv.w * (1.0f / yv.w) : 0.0f;
        o4[i] = ov;
    }
}

// Scalar tail for n % 4 != 0 (not hit at the bench shape, kept for safety).
__global__ void __launch_bounds__(64)
StableZeroDiv_16561393894029_tail(const float* __restrict__ x,
                                  const float* __restrict__ y,
                                  float* __restrict__ o,
                                  int start, int n) {
    int i = start + blockIdx.x * blockDim.x + threadIdx.x;
    if (i < n) {
        float yv = y[i];
        o[i] = (yv != 0.0f) ? x[i] * (1.0f / yv) : 0.0f;
    }
}

extern "C" void kernel_launch(void* const* d_in, const int* in_sizes, int n_in,
                              void* d_out, int out_size, void* d_ws, size_t ws_size,
                              hipStream_t stream) {
    const float* x = (const float*)d_in[0];
    const float* y = (const float*)d_in[1];
    float* out = (float*)d_out;
    const int n = in_sizes[0];          // 67,108,864
    const int n4 = n / 4;               // 16,777,216 float4 elements

    // Grid: cap at 256 CUs x 8 blocks/CU = 2048 blocks; grid-stride the rest.
    const int block = 256;
    int grid = (n4 + block - 1) / block;
    if (grid > 2048) grid = 2048;
    if (grid < 1) grid = 1;

    StableZeroDiv_16561393894029_kernel<<<grid, block, 0, stream>>>(
        (const float4*)x, (const float4*)y, (float4*)out, n4);

    const int tail_start = n4 * 4;
    const int tail_n = n - tail_start;
    if (tail_n > 0) {
        StableZeroDiv_16561393894029_tail<<<1, 64, 0, stream>>>(
            x, y, out, tail_start, n);
    }
}